// Round 7
// baseline (282.509 us; speedup 1.0000x reference)
//
#include <hip/hip_runtime.h>

#define S_ 1024
#define H_ 16
#define D_ 32

typedef float f32x4 __attribute__((ext_vector_type(4)));
typedef short bf16x8 __attribute__((ext_vector_type(8)));
typedef unsigned long long u64;

static __device__ __forceinline__ short f2b(float f) {
    union { float f; unsigned u; } x; x.f = f;
    unsigned u = x.u;
    unsigned r = u + 0x7fffu + ((u >> 16) & 1u);
    return (short)(r >> 16);
}
static __device__ __forceinline__ unsigned pk_rne(float lo, float hi) {
    union { float f; unsigned u; } a, b; a.f = lo; b.f = hi;
    unsigned ul = a.u + 0x7fffu + ((a.u >> 16) & 1u);
    unsigned uh = b.u + 0x7fffu + ((b.u >> 16) & 1u);
    return __builtin_amdgcn_perm(uh, ul, 0x07060302u);
}
static __device__ __forceinline__ unsigned pk_trunc(float lo, float hi) {
    union { float f; unsigned u; } a, b; a.f = lo; b.f = hi;
    return __builtin_amdgcn_perm(b.u, a.u, 0x07060302u);
}
static __device__ __forceinline__ float bperm(int bidx, float v) {
    union { float f; int i; } x; x.f = v;
    x.i = __builtin_amdgcn_ds_bpermute(bidx, x.i);
    return x.f;
}
// LDS staging offset, 64-col tiles (pitch 72), XOR swizzle
static __device__ __forceinline__ int stg64(int row, int c8) {
    return row * 72 + (c8 ^ ((row & 3) << 3));
}

// ---------------- prep: relb cvt + mask pack + W transpose ----------------
__global__ __launch_bounds__(256)
void prep_kernel(const float* __restrict__ rt, short* __restrict__ relb,
                 const int* __restrict__ mask, u64* __restrict__ mbits,
                 const float* __restrict__ Wq, const float* __restrict__ Wk,
                 const float* __restrict__ Wv, const float* __restrict__ Wo,
                 short* __restrict__ Wt)
{
    __shared__ float ls[32][33];
    int bid = blockIdx.x, t = threadIdx.x;
    if (bid < 257) {                                   // rel_table -> bf16 (65568 elems)
        int i = bid * 256 + t;
        if (i < 2049 * 32) relb[i] = f2b(rt[i]);
        return;
    }
    bid -= 257;
    if (bid < 4096) {                                  // mask bit-pack (4M ints -> 64K u64)
        #pragma unroll
        for (int j = 0; j < 4; ++j) {
            int i = bid * 1024 + j * 256 + t;
            u64 bal = __ballot(mask[i] > 0);
            if ((t & 63) == 0) mbits[i >> 6] = bal;
        }
        return;
    }
    bid -= 4096;                                       // W transpose -> bf16 [mat][n][k], 1024 blocks
    int mat = bid >> 8, tl = bid & 255, ti = tl >> 4, tj = tl & 15;
    const float* W = (mat == 0) ? Wq : (mat == 1) ? Wk : (mat == 2) ? Wv : Wo;
    int r = t >> 3, c = (t & 7) * 4;
    float4 v = *(const float4*)(W + (long)(ti * 32 + r) * 512 + tj * 32 + c);
    ls[r][c] = v.x; ls[r][c + 1] = v.y; ls[r][c + 2] = v.z; ls[r][c + 3] = v.w;
    __syncthreads();
    int nl = t >> 3, kk = (t & 7) * 4;
    uint2 o = { pk_rne(ls[kk][nl], ls[kk + 1][nl]),
                pk_rne(ls[kk + 2][nl], ls[kk + 3][nl]) };
    *(uint2*)(Wt + ((long)mat * 512 + tj * 32 + nl) * 512 + ti * 32 + kk) = o;
}

// ---------------- fused projection GEMMs: qh, kh, vt (64x64 tiles, BK=64) ----------------
__global__ __launch_bounds__(256)
void gemm3_kernel(const float* __restrict__ q, const float* __restrict__ kv,
                  const short* __restrict__ Wt,
                  short* __restrict__ qh, short* __restrict__ kh, short* __restrict__ vt,
                  float scale)
{
    __shared__ __align__(16) short a_s[64 * 72];
    __shared__ __align__(16) short b_s[64 * 72];
    const int t = threadIdx.x;
    const int w = t >> 6, lane = t & 63, l15 = lane & 15, quad = lane >> 4;
    const int wm = w & 1, wn = w >> 1;

    int bid = blockIdx.x;
    const int mat = bid >> 9;                  // 0:q@Wq 1:kv@Wk 2:kv@Wv
    const int rr_ = bid & 511;
    const int bm = (rr_ >> 3) * 64, bn = (rr_ & 7) * 64;
    const float* A = (mat == 0) ? q : kv;
    const short* Wm = Wt + (long)mat * 262144;

    const int srow = t >> 2, scg = (t & 3) << 4;       // row 0..63, col group 0/16/32/48
    f32x4 acc[2][2] = {};

    for (int k0 = 0; k0 < 512; k0 += 64) {
        {
            const float* ap = A + (long)(bm + srow) * 512 + k0 + scg;
            float4 v0 = *(const float4*)(ap);
            float4 v1 = *(const float4*)(ap + 4);
            float4 v2 = *(const float4*)(ap + 8);
            float4 v3 = *(const float4*)(ap + 12);
            uint4 o0 = { pk_rne(v0.x, v0.y), pk_rne(v0.z, v0.w),
                         pk_rne(v1.x, v1.y), pk_rne(v1.z, v1.w) };
            uint4 o1 = { pk_rne(v2.x, v2.y), pk_rne(v2.z, v2.w),
                         pk_rne(v3.x, v3.y), pk_rne(v3.z, v3.w) };
            *(uint4*)(a_s + stg64(srow, scg)) = o0;
            *(uint4*)(a_s + stg64(srow, scg + 8)) = o1;
        }
        {
            const short* bp = Wm + (long)(bn + srow) * 512 + k0 + scg;
            *(bf16x8*)(b_s + stg64(srow, scg))     = *(const bf16x8*)(bp);
            *(bf16x8*)(b_s + stg64(srow, scg + 8)) = *(const bf16x8*)(bp + 8);
        }
        __syncthreads();
        bf16x8 af[2][2], bfr[2][2];
        #pragma unroll
        for (int i = 0; i < 2; ++i)
            #pragma unroll
            for (int ks = 0; ks < 2; ++ks) {
                af[i][ks]  = *(const bf16x8*)(a_s + stg64(wm * 32 + i * 16 + l15, ks * 32 + quad * 8));
                bfr[i][ks] = *(const bf16x8*)(b_s + stg64(wn * 32 + i * 16 + l15, ks * 32 + quad * 8));
            }
        if (mat == 2) {
            #pragma unroll
            for (int i = 0; i < 2; ++i)
                #pragma unroll
                for (int j = 0; j < 2; ++j)
                    #pragma unroll
                    for (int ks = 0; ks < 2; ++ks)
                        acc[i][j] = __builtin_amdgcn_mfma_f32_16x16x32_bf16(bfr[i][ks], af[j][ks], acc[i][j], 0, 0, 0);
        } else {
            #pragma unroll
            for (int i = 0; i < 2; ++i)
                #pragma unroll
                for (int j = 0; j < 2; ++j)
                    #pragma unroll
                    for (int ks = 0; ks < 2; ++ks)
                        acc[i][j] = __builtin_amdgcn_mfma_f32_16x16x32_bf16(af[i][ks], bfr[j][ks], acc[i][j], 0, 0, 0);
        }
        __syncthreads();
    }

    if (mat < 2) {
        short* out = (mat == 0) ? qh : kh;
        float alpha = (mat == 0) ? scale : 1.0f;
        #pragma unroll
        for (int i = 0; i < 2; ++i)
            #pragma unroll
            for (int j = 0; j < 2; ++j)
                #pragma unroll
                for (int r = 0; r < 4; ++r) {
                    int m = bm + wm * 32 + i * 16 + quad * 4 + r;
                    int n = bn + wn * 32 + j * 16 + l15;
                    int bb = m >> 10, s = m & 1023, hh = n >> 5, dd = n & 31;
                    out[((long)((bb * 16 + hh) * 1024 + s)) * 32 + dd] = f2b(acc[i][j][r] * alpha);
                }
    } else {
        #pragma unroll
        for (int i = 0; i < 2; ++i)
            #pragma unroll
            for (int j = 0; j < 2; ++j)
                #pragma unroll
                for (int r = 0; r < 4; ++r) {
                    int n = bn + wn * 32 + i * 16 + quad * 4 + r;   // feature (h,d)
                    int m = bm + wm * 32 + j * 16 + l15;            // token
                    int bb = m >> 10, s = m & 1023, hh = n >> 5, dd = n & 31;
                    int sp = (s & ~63) | ((s & 15) << 2) | ((s >> 4) & 3); // k-permute
                    vt[((long)((bb * 16 + hh) * 32 + dd)) * 1024 + sp] = f2b(acc[i][j][r]);
                }
    }
}

// ---------------- output GEMM: d_out = ao @ Wo (BK=64) ----------------
__global__ __launch_bounds__(256)
void gemm_out_kernel(const short* __restrict__ ao, const short* __restrict__ Wt,
                     float* __restrict__ out)
{
    __shared__ __align__(16) short a_s[64 * 72];
    __shared__ __align__(16) short b_s[64 * 72];
    const int t = threadIdx.x;
    const int w = t >> 6, lane = t & 63, l15 = lane & 15, quad = lane >> 4;
    const int wm = w & 1, wn = w >> 1;
    const int bm = (blockIdx.x >> 3) * 64, bn = (blockIdx.x & 7) * 64;
    const short* Wm = Wt + (long)3 * 262144;
    const int srow = t >> 2, scg = (t & 3) << 4;
    f32x4 acc[2][2] = {};

    for (int k0 = 0; k0 < 512; k0 += 64) {
        {
            const short* apb = ao + (long)(bm + srow) * 512 + k0 + scg;
            *(bf16x8*)(a_s + stg64(srow, scg))     = *(const bf16x8*)(apb);
            *(bf16x8*)(a_s + stg64(srow, scg + 8)) = *(const bf16x8*)(apb + 8);
            const short* bpb = Wm + (long)(bn + srow) * 512 + k0 + scg;
            *(bf16x8*)(b_s + stg64(srow, scg))     = *(const bf16x8*)(bpb);
            *(bf16x8*)(b_s + stg64(srow, scg + 8)) = *(const bf16x8*)(bpb + 8);
        }
        __syncthreads();
        bf16x8 af[2][2], bfr[2][2];
        #pragma unroll
        for (int i = 0; i < 2; ++i)
            #pragma unroll
            for (int ks = 0; ks < 2; ++ks) {
                af[i][ks]  = *(const bf16x8*)(a_s + stg64(wm * 32 + i * 16 + l15, ks * 32 + quad * 8));
                bfr[i][ks] = *(const bf16x8*)(b_s + stg64(wn * 32 + i * 16 + l15, ks * 32 + quad * 8));
            }
        #pragma unroll
        for (int i = 0; i < 2; ++i)
            #pragma unroll
            for (int j = 0; j < 2; ++j)
                #pragma unroll
                for (int ks = 0; ks < 2; ++ks)
                    acc[i][j] = __builtin_amdgcn_mfma_f32_16x16x32_bf16(af[i][ks], bfr[j][ks], acc[i][j], 0, 0, 0);
        __syncthreads();
    }
    #pragma unroll
    for (int i = 0; i < 2; ++i)
        #pragma unroll
        for (int j = 0; j < 2; ++j)
            #pragma unroll
            for (int r = 0; r < 4; ++r) {
                int m = bm + wm * 32 + i * 16 + quad * 4 + r;
                int n = bn + wn * 32 + j * 16 + l15;
                out[(long)m * 512 + n] = acc[i][j][r];
            }
}

// ---------------- fused attention v5: 2-way split-K, straight-sum softmax ----------------
// Block = 4 waves = 2 q-tiles x 2 k-halves (8 chunks of 64 each). Straight-sum partials
// (l, O) combine linearly across halves via LDS + one __syncthreads.
__global__ __launch_bounds__(256, 4)
void attn_kernel(const short* __restrict__ qh, const float* __restrict__ wrel,
                 const short* __restrict__ kh, const short* __restrict__ vt,
                 const short* __restrict__ relb, const u64* __restrict__ mbits,
                 short* __restrict__ ao)
{
    __shared__ __align__(16) short smem[4 * 2 * 16 * 72];
    const int t = threadIdx.x;
    const int w = t >> 6, lane = t & 63, l15 = lane & 15, quad = lane >> 4;
    short* pw0 = smem + w * (2 * 16 * 72);
    short* pw1 = pw0 + 16 * 72;

    const int half = w & 1, qsel = w >> 1;
    const int gw = blockIdx.x * 2 + qsel;              // q-tile id, 0..4095
    const int qt = gw & 63, h = (gw >> 6) & 15, b = gw >> 10;
    const int q0 = qt * 16, bh = b * H_ + h;
    const int c0 = half * 8;

    const long qbase = ((long)bh * S_ + q0 + l15) * D_ + quad * 8;
    const bf16x8 a_qh = *(const bf16x8*)(qh + qbase);
    const long kv_bh = (long)bh * S_ * D_;
    const u64* mrow = mbits + ((long)b * S_ + q0 + quad * 4) * 16;

    // ---- inline QR (2 MFMAs + LDS transpose) ----
    bf16x8 a_qr;
    {
        #pragma unroll
        for (int nt = 0; nt < 2; ++nt) {
            const float* wp = wrel + (long)(nt * 16 + l15) * 32 + quad * 8;
            float4 w0 = *(const float4*)(wp);
            float4 w1 = *(const float4*)(wp + 4);
            bf16x8 bw;
            *(uint4*)&bw = (uint4){ pk_rne(w0.x, w0.y), pk_rne(w0.z, w0.w),
                                    pk_rne(w1.x, w1.y), pk_rne(w1.z, w1.w) };
            f32x4 z = {0.f, 0.f, 0.f, 0.f};
            f32x4 cq = __builtin_amdgcn_mfma_f32_16x16x32_bf16(a_qh, bw, z, 0, 0, 0);
            #pragma unroll
            for (int r = 0; r < 4; ++r)
                pw0[(quad * 4 + r) * 36 + nt * 16 + l15] = f2b(cq[r]);
        }
        asm volatile("" ::: "memory");
        a_qr = *(const bf16x8*)(pw0 + l15 * 36 + quad * 8);
        asm volatile("" ::: "memory");
    }

    int bidx[4]; int cnd[4];
    #pragma unroll
    for (int r = 0; r < 4; ++r) {
        int qq = quad * 4 + r;
        bidx[r] = (quad * 16 + ((l15 + 15 - qq) & 15)) * 4;
        cnd[r] = (l15 > qq);
    }

    f32x4 oacc[2] = {};
    float l4[4] = {0.f, 0.f, 0.f, 0.f};

    bf16x8 preg0 = {}, preg1 = {};
    bf16x8 bv00 = {}, bv01 = {}, bv10 = {}, bv11 = {};

    // prologue: rel/K fragments + mask words for chunk c0 (issue order = consume order)
    bf16x8 kf[4], rf[5];
    u64 mcur[4];
    {
        const int ub0 = c0 * 64 - q0 + (S_ - 15);
        #pragma unroll
        for (int ut = 0; ut < 5; ++ut)
            rf[ut] = *(const bf16x8*)(relb + (long)(ub0 + ut * 16 + l15) * D_ + quad * 8);
        #pragma unroll
        for (int kt = 0; kt < 4; ++kt)
            kf[kt] = *(const bf16x8*)(kh + kv_bh + (long)(c0 * 64 + kt * 16 + l15) * D_ + quad * 8);
        #pragma unroll
        for (int r = 0; r < 4; ++r) mcur[r] = mrow[r * 16 + c0];
    }

    #pragma unroll
    for (int i = 0; i < 8; ++i) {
        const int c = c0 + i;
        const int kbase = c * 64;
        short* pwbuf = (i & 1) ? pw1 : pw0;

        // consume prefetched rel/K fragments (9 independent MFMAs)
        f32x4 ctf[5], sc[4];
        #pragma unroll
        for (int ut = 0; ut < 5; ++ut) {
            f32x4 z = {0.f, 0.f, 0.f, 0.f};
            ctf[ut] = __builtin_amdgcn_mfma_f32_16x16x32_bf16(a_qr, rf[ut], z, 0, 0, 0);
        }
        #pragma unroll
        for (int kt = 0; kt < 4; ++kt) {
            f32x4 z = {0.f, 0.f, 0.f, 0.f};
            sc[kt] = __builtin_amdgcn_mfma_f32_16x16x32_bf16(a_qh, kf[kt], z, 0, 0, 0);
        }
        // PV for previous chunk
        if (i) {
            oacc[0] = __builtin_amdgcn_mfma_f32_16x16x32_bf16(preg0, bv00, oacc[0], 0, 0, 0);
            oacc[1] = __builtin_amdgcn_mfma_f32_16x16x32_bf16(preg0, bv01, oacc[1], 0, 0, 0);
            oacc[0] = __builtin_amdgcn_mfma_f32_16x16x32_bf16(preg1, bv10, oacc[0], 0, 0, 0);
            oacc[1] = __builtin_amdgcn_mfma_f32_16x16x32_bf16(preg1, bv11, oacc[1], 0, 0, 0);
        }
        // prefetch for next chunk: rel/K first, then mask, then V(this chunk)
        u64 mnext[4];
        if (i < 7) {
            const int kbn = kbase + 64, ubn = kbn - q0 + (S_ - 15);
            #pragma unroll
            for (int ut = 0; ut < 5; ++ut)
                rf[ut] = *(const bf16x8*)(relb + (long)(ubn + ut * 16 + l15) * D_ + quad * 8);
            #pragma unroll
            for (int kt = 0; kt < 4; ++kt)
                kf[kt] = *(const bf16x8*)(kh + kv_bh + (long)(kbn + kt * 16 + l15) * D_ + quad * 8);
            #pragma unroll
            for (int r = 0; r < 4; ++r) mnext[r] = mrow[r * 16 + c + 1];
        }
        bv00 = *(const bf16x8*)(vt + kv_bh + (long)(l15) * S_ + kbase + quad * 8);
        bv01 = *(const bf16x8*)(vt + kv_bh + (long)(16 + l15) * S_ + kbase + quad * 8);
        bv10 = *(const bf16x8*)(vt + kv_bh + (long)(l15) * S_ + kbase + 32 + quad * 8);
        bv11 = *(const bf16x8*)(vt + kv_bh + (long)(16 + l15) * S_ + kbase + 32 + quad * 8);

        // bias shear (bpermute) + straight-sum exp + mask
        #pragma unroll
        for (int r = 0; r < 4; ++r) {
            float tt[5];
            #pragma unroll
            for (int ut = 0; ut < 5; ++ut) tt[ut] = bperm(bidx[r], ctf[ut][r]);
            float s0 = sc[0][r] + (cnd[r] ? tt[1] : tt[0]);
            float s1 = sc[1][r] + (cnd[r] ? tt[2] : tt[1]);
            float s2 = sc[2][r] + (cnd[r] ? tt[3] : tt[2]);
            float s3 = sc[3][r] + (cnd[r] ? tt[4] : tt[3]);
            u64 mw = mcur[r] >> l15;
            unsigned lo = (unsigned)mw, hi = (unsigned)(mw >> 32);
            float p0 = __expf(s0); p0 = (lo & 1u)         ? p0 : 0.f;
            float p1 = __expf(s1); p1 = ((lo >> 16) & 1u) ? p1 : 0.f;
            float p2 = __expf(s2); p2 = (hi & 1u)         ? p2 : 0.f;
            float p3 = __expf(s3); p3 = ((hi >> 16) & 1u) ? p3 : 0.f;
            l4[r] += (p0 + p1) + (p2 + p3);
            u64 pv = ((u64)pk_trunc(p2, p3) << 32) | (u64)pk_trunc(p0, p1);
            *(u64*)(pwbuf + (quad * 4 + r) * 72 + l15 * 4) = pv;
        }
        asm volatile("" ::: "memory");
        preg0 = *(const bf16x8*)(pwbuf + l15 * 72 + quad * 8);
        preg1 = *(const bf16x8*)(pwbuf + l15 * 72 + 32 + quad * 8);
        if (i < 7) {
            #pragma unroll
            for (int r = 0; r < 4; ++r) mcur[r] = mnext[r];
        }
    }
    // final PV
    oacc[0] = __builtin_amdgcn_mfma_f32_16x16x32_bf16(preg0, bv00, oacc[0], 0, 0, 0);
    oacc[1] = __builtin_amdgcn_mfma_f32_16x16x32_bf16(preg0, bv01, oacc[1], 0, 0, 0);
    oacc[0] = __builtin_amdgcn_mfma_f32_16x16x32_bf16(preg1, bv10, oacc[0], 0, 0, 0);
    oacc[1] = __builtin_amdgcn_mfma_f32_16x16x32_bf16(preg1, bv11, oacc[1], 0, 0, 0);

    // per-wave row sums
    #pragma unroll
    for (int r = 0; r < 4; ++r) {
        float l = l4[r];
        l += __shfl_xor(l, 1, 64);
        l += __shfl_xor(l, 2, 64);
        l += __shfl_xor(l, 4, 64);
        l += __shfl_xor(l, 8, 64);
        l4[r] = l;
    }

    // cross-half combine: write partials into own (now dead) P area, sync, partner adds
    asm volatile("" ::: "memory");
    float* fo = (float*)pw0;                           // [16 rows][32 d] f32 (2048B < 2304B)
    float* fl = (float*)pw1;                           // [16 rows] f32
    #pragma unroll
    for (int r = 0; r < 4; ++r) {
        #pragma unroll
        for (int dt = 0; dt < 2; ++dt)
            fo[(quad * 4 + r) * 32 + dt * 16 + l15] = oacc[dt][r];
        if (l15 == 0) fl[quad * 4 + r] = l4[r];
    }
    __syncthreads();
    if (half == 0) {
        const float* po = (const float*)(smem + (w ^ 1) * (2 * 16 * 72));
        const float* pl = po + 16 * 72 / 2;            // partner pw1 as float*
        #pragma unroll
        for (int r = 0; r < 4; ++r) {
            int row = quad * 4 + r;
            float inv = 1.0f / (l4[r] + pl[row]);
            #pragma unroll
            for (int dt = 0; dt < 2; ++dt) {
                float o = oacc[dt][r] + po[row * 32 + dt * 16 + l15];
                ao[((long)(b * S_ + q0 + row) * H_ + h) * D_ + dt * 16 + l15] = f2b(o * inv);
            }
        }
    }
}

extern "C" void kernel_launch(void* const* d_in, const int* in_sizes, int n_in,
                              void* d_out, int out_size, void* d_ws, size_t ws_size,
                              hipStream_t stream) {
    (void)in_sizes; (void)n_in; (void)out_size; (void)ws_size;
    const float* kv   = (const float*)d_in[0];
    const float* q    = (const float*)d_in[1];
    const int*   mask = (const int*)d_in[2];
    const float* Wq   = (const float*)d_in[3];
    const float* Wk   = (const float*)d_in[4];
    const float* Wv   = (const float*)d_in[5];
    const float* Wo   = (const float*)d_in[6];
    const float* rt   = (const float*)d_in[7];
    const float* Wrel = (const float*)d_in[8];

    // workspace map — 18.75 MB total (proven safe)
    char* ws = (char*)d_ws;
    short* qh   = (short*)(ws);                      // [B,H,S,D] bf16, 4MB
    short* kh   = (short*)(ws + (4u  << 20));        // [B,H,S,D] 4MB
    short* vt   = (short*)(ws + (8u  << 20));        // [B,H,D,S'] k-permuted, 4MB
    short* ao   = (short*)(ws + (12u << 20));        // [B,S,H,D] 4MB
    short* Wt   = (short*)(ws + (16u << 20));        // 4x[512n][512k] bf16, 2MB
    short* relb = (short*)(ws + (18u << 20));        // [2049,32] bf16, 128KB
    u64*  mbits = (u64*) (ws + (18u << 20) + (256u << 10));  // 512KB

    const float scale = 0.17677669529663687f;        // 1/sqrt(32) folded into QH (and thus QR)

    prep_kernel<<<257 + 4096 + 1024, 256, 0, stream>>>(
        rt, relb, mask, mbits, Wq, Wk, Wv, Wo, Wt);

    gemm3_kernel<<<1536, 256, 0, stream>>>(q, kv, Wt, qh, kh, vt, scale);

    attn_kernel<<<2048, 256, 0, stream>>>(qh, Wrel, kh, vt, relb, mbits, ao);

    gemm_out_kernel<<<512, 256, 0, stream>>>(ao, Wt, (float*)d_out);
}

// Round 8
// 227.716 us; speedup vs baseline: 1.2406x; 1.2406x over previous
//
#include <hip/hip_runtime.h>

#define S_ 1024
#define H_ 16
#define D_ 32

typedef float f32x4 __attribute__((ext_vector_type(4)));
typedef short bf16x8 __attribute__((ext_vector_type(8)));
typedef unsigned long long u64;

static __device__ __forceinline__ short f2b(float f) {
    union { float f; unsigned u; } x; x.f = f;
    unsigned u = x.u;
    unsigned r = u + 0x7fffu + ((u >> 16) & 1u);
    return (short)(r >> 16);
}
static __device__ __forceinline__ unsigned pk_rne(float lo, float hi) {
    union { float f; unsigned u; } a, b; a.f = lo; b.f = hi;
    unsigned ul = a.u + 0x7fffu + ((a.u >> 16) & 1u);
    unsigned uh = b.u + 0x7fffu + ((b.u >> 16) & 1u);
    return __builtin_amdgcn_perm(uh, ul, 0x07060302u);
}
static __device__ __forceinline__ unsigned pk_trunc(float lo, float hi) {
    union { float f; unsigned u; } a, b; a.f = lo; b.f = hi;
    return __builtin_amdgcn_perm(b.u, a.u, 0x07060302u);
}
static __device__ __forceinline__ float bperm(int bidx, float v) {
    union { float f; int i; } x; x.f = v;
    x.i = __builtin_amdgcn_ds_bpermute(bidx, x.i);
    return x.f;
}
// LDS staging offset, 64-col tiles (pitch 72), XOR swizzle
static __device__ __forceinline__ int stg64(int row, int c8) {
    return row * 72 + (c8 ^ ((row & 3) << 3));
}

// ---------------- prep: relb cvt + mask pack + W transpose ----------------
__global__ __launch_bounds__(256)
void prep_kernel(const float* __restrict__ rt, short* __restrict__ relb,
                 const int* __restrict__ mask, u64* __restrict__ mbits,
                 const float* __restrict__ Wq, const float* __restrict__ Wk,
                 const float* __restrict__ Wv, const float* __restrict__ Wo,
                 short* __restrict__ Wt)
{
    __shared__ float ls[32][33];
    int bid = blockIdx.x, t = threadIdx.x;
    if (bid < 257) {                                   // rel_table -> bf16 (65568 elems)
        int i = bid * 256 + t;
        if (i < 2049 * 32) relb[i] = f2b(rt[i]);
        return;
    }
    bid -= 257;
    if (bid < 4096) {                                  // mask bit-pack (4M ints -> 64K u64)
        #pragma unroll
        for (int j = 0; j < 4; ++j) {
            int i = bid * 1024 + j * 256 + t;
            u64 bal = __ballot(mask[i] > 0);
            if ((t & 63) == 0) mbits[i >> 6] = bal;
        }
        return;
    }
    bid -= 4096;                                       // W transpose -> bf16 [mat][n][k], 1024 blocks
    int mat = bid >> 8, tl = bid & 255, ti = tl >> 4, tj = tl & 15;
    const float* W = (mat == 0) ? Wq : (mat == 1) ? Wk : (mat == 2) ? Wv : Wo;
    int r = t >> 3, c = (t & 7) * 4;
    float4 v = *(const float4*)(W + (long)(ti * 32 + r) * 512 + tj * 32 + c);
    ls[r][c] = v.x; ls[r][c + 1] = v.y; ls[r][c + 2] = v.z; ls[r][c + 3] = v.w;
    __syncthreads();
    int nl = t >> 3, kk = (t & 7) * 4;
    uint2 o = { pk_rne(ls[kk][nl], ls[kk + 1][nl]),
                pk_rne(ls[kk + 2][nl], ls[kk + 3][nl]) };
    *(uint2*)(Wt + ((long)mat * 512 + tj * 32 + nl) * 512 + ti * 32 + kk) = o;
}

// ---------------- fused projection GEMMs: qh, kh, vt (64x64 tiles, BK=64) ----------------
__global__ __launch_bounds__(256)
void gemm3_kernel(const float* __restrict__ q, const float* __restrict__ kv,
                  const short* __restrict__ Wt,
                  short* __restrict__ qh, short* __restrict__ kh, short* __restrict__ vt,
                  float scale)
{
    __shared__ __align__(16) short a_s[64 * 72];
    __shared__ __align__(16) short b_s[64 * 72];
    const int t = threadIdx.x;
    const int w = t >> 6, lane = t & 63, l15 = lane & 15, quad = lane >> 4;
    const int wm = w & 1, wn = w >> 1;

    int bid = blockIdx.x;
    const int mat = bid >> 9;                  // 0:q@Wq 1:kv@Wk 2:kv@Wv
    const int rr_ = bid & 511;
    const int bm = (rr_ >> 3) * 64, bn = (rr_ & 7) * 64;
    const float* A = (mat == 0) ? q : kv;
    const short* Wm = Wt + (long)mat * 262144;

    const int srow = t >> 2, scg = (t & 3) << 4;       // row 0..63, col group 0/16/32/48
    f32x4 acc[2][2] = {};

    for (int k0 = 0; k0 < 512; k0 += 64) {
        {
            const float* ap = A + (long)(bm + srow) * 512 + k0 + scg;
            float4 v0 = *(const float4*)(ap);
            float4 v1 = *(const float4*)(ap + 4);
            float4 v2 = *(const float4*)(ap + 8);
            float4 v3 = *(const float4*)(ap + 12);
            uint4 o0 = { pk_rne(v0.x, v0.y), pk_rne(v0.z, v0.w),
                         pk_rne(v1.x, v1.y), pk_rne(v1.z, v1.w) };
            uint4 o1 = { pk_rne(v2.x, v2.y), pk_rne(v2.z, v2.w),
                         pk_rne(v3.x, v3.y), pk_rne(v3.z, v3.w) };
            *(uint4*)(a_s + stg64(srow, scg)) = o0;
            *(uint4*)(a_s + stg64(srow, scg + 8)) = o1;
        }
        {
            const short* bp = Wm + (long)(bn + srow) * 512 + k0 + scg;
            *(bf16x8*)(b_s + stg64(srow, scg))     = *(const bf16x8*)(bp);
            *(bf16x8*)(b_s + stg64(srow, scg + 8)) = *(const bf16x8*)(bp + 8);
        }
        __syncthreads();
        bf16x8 af[2][2], bfr[2][2];
        #pragma unroll
        for (int i = 0; i < 2; ++i)
            #pragma unroll
            for (int ks = 0; ks < 2; ++ks) {
                af[i][ks]  = *(const bf16x8*)(a_s + stg64(wm * 32 + i * 16 + l15, ks * 32 + quad * 8));
                bfr[i][ks] = *(const bf16x8*)(b_s + stg64(wn * 32 + i * 16 + l15, ks * 32 + quad * 8));
            }
        if (mat == 2) {
            #pragma unroll
            for (int i = 0; i < 2; ++i)
                #pragma unroll
                for (int j = 0; j < 2; ++j)
                    #pragma unroll
                    for (int ks = 0; ks < 2; ++ks)
                        acc[i][j] = __builtin_amdgcn_mfma_f32_16x16x32_bf16(bfr[i][ks], af[j][ks], acc[i][j], 0, 0, 0);
        } else {
            #pragma unroll
            for (int i = 0; i < 2; ++i)
                #pragma unroll
                for (int j = 0; j < 2; ++j)
                    #pragma unroll
                    for (int ks = 0; ks < 2; ++ks)
                        acc[i][j] = __builtin_amdgcn_mfma_f32_16x16x32_bf16(af[i][ks], bfr[j][ks], acc[i][j], 0, 0, 0);
        }
        __syncthreads();
    }

    if (mat < 2) {
        short* out = (mat == 0) ? qh : kh;
        float alpha = (mat == 0) ? scale : 1.0f;
        #pragma unroll
        for (int i = 0; i < 2; ++i)
            #pragma unroll
            for (int j = 0; j < 2; ++j)
                #pragma unroll
                for (int r = 0; r < 4; ++r) {
                    int m = bm + wm * 32 + i * 16 + quad * 4 + r;
                    int n = bn + wn * 32 + j * 16 + l15;
                    int bb = m >> 10, s = m & 1023, hh = n >> 5, dd = n & 31;
                    out[((long)((bb * 16 + hh) * 1024 + s)) * 32 + dd] = f2b(acc[i][j][r] * alpha);
                }
    } else {
        #pragma unroll
        for (int i = 0; i < 2; ++i)
            #pragma unroll
            for (int j = 0; j < 2; ++j)
                #pragma unroll
                for (int r = 0; r < 4; ++r) {
                    int n = bn + wn * 32 + i * 16 + quad * 4 + r;   // feature (h,d)
                    int m = bm + wm * 32 + j * 16 + l15;            // token
                    int bb = m >> 10, s = m & 1023, hh = n >> 5, dd = n & 31;
                    int sp = (s & ~63) | ((s & 15) << 2) | ((s >> 4) & 3); // k-permute
                    vt[((long)((bb * 16 + hh) * 32 + dd)) * 1024 + sp] = f2b(acc[i][j][r]);
                }
    }
}

// ---------------- output GEMM: d_out = ao @ Wo (BK=64) ----------------
__global__ __launch_bounds__(256)
void gemm_out_kernel(const short* __restrict__ ao, const short* __restrict__ Wt,
                     float* __restrict__ out)
{
    __shared__ __align__(16) short a_s[64 * 72];
    __shared__ __align__(16) short b_s[64 * 72];
    const int t = threadIdx.x;
    const int w = t >> 6, lane = t & 63, l15 = lane & 15, quad = lane >> 4;
    const int wm = w & 1, wn = w >> 1;
    const int bm = (blockIdx.x >> 3) * 64, bn = (blockIdx.x & 7) * 64;
    const short* Wm = Wt + (long)3 * 262144;
    const int srow = t >> 2, scg = (t & 3) << 4;
    f32x4 acc[2][2] = {};

    for (int k0 = 0; k0 < 512; k0 += 64) {
        {
            const short* apb = ao + (long)(bm + srow) * 512 + k0 + scg;
            *(bf16x8*)(a_s + stg64(srow, scg))     = *(const bf16x8*)(apb);
            *(bf16x8*)(a_s + stg64(srow, scg + 8)) = *(const bf16x8*)(apb + 8);
            const short* bpb = Wm + (long)(bn + srow) * 512 + k0 + scg;
            *(bf16x8*)(b_s + stg64(srow, scg))     = *(const bf16x8*)(bpb);
            *(bf16x8*)(b_s + stg64(srow, scg + 8)) = *(const bf16x8*)(bpb + 8);
        }
        __syncthreads();
        bf16x8 af[2][2], bfr[2][2];
        #pragma unroll
        for (int i = 0; i < 2; ++i)
            #pragma unroll
            for (int ks = 0; ks < 2; ++ks) {
                af[i][ks]  = *(const bf16x8*)(a_s + stg64(wm * 32 + i * 16 + l15, ks * 32 + quad * 8));
                bfr[i][ks] = *(const bf16x8*)(b_s + stg64(wn * 32 + i * 16 + l15, ks * 32 + quad * 8));
            }
        #pragma unroll
        for (int i = 0; i < 2; ++i)
            #pragma unroll
            for (int j = 0; j < 2; ++j)
                #pragma unroll
                for (int ks = 0; ks < 2; ++ks)
                    acc[i][j] = __builtin_amdgcn_mfma_f32_16x16x32_bf16(af[i][ks], bfr[j][ks], acc[i][j], 0, 0, 0);
        __syncthreads();
    }
    #pragma unroll
    for (int i = 0; i < 2; ++i)
        #pragma unroll
        for (int j = 0; j < 2; ++j)
            #pragma unroll
            for (int r = 0; r < 4; ++r) {
                int m = bm + wm * 32 + i * 16 + quad * 4 + r;
                int n = bn + wn * 32 + j * 16 + l15;
                out[(long)m * 512 + n] = acc[i][j][r];
            }
}

// ---------------- fused attention v6: 2-way split-K, round-6 register discipline ----------------
// Wave = (q-tile, k-half of 8 chunks). Dynamic loop (NO unroll — r7's unroll caused VGPR
// spill: WRITE_SIZE 375MB of scratch). Mask loaded inline (r6 style). Straight-sum partials
// combine linearly across halves via LDS + one __syncthreads.
__global__ __launch_bounds__(256, 4)
void attn_kernel(const short* __restrict__ qh, const float* __restrict__ wrel,
                 const short* __restrict__ kh, const short* __restrict__ vt,
                 const short* __restrict__ relb, const u64* __restrict__ mbits,
                 short* __restrict__ ao)
{
    __shared__ __align__(16) short smem[4 * 2 * 16 * 72];
    const int t = threadIdx.x;
    const int w = t >> 6, lane = t & 63, l15 = lane & 15, quad = lane >> 4;
    short* pw0 = smem + w * (2 * 16 * 72);
    short* pw1 = pw0 + 16 * 72;

    const int half = w & 1, qsel = w >> 1;
    const int gw = blockIdx.x * 2 + qsel;              // q-tile id, 0..4095
    const int qt = gw & 63, h = (gw >> 6) & 15, b = gw >> 10;
    const int q0 = qt * 16, bh = b * H_ + h;
    const int c0 = half * 8;

    const long qbase = ((long)bh * S_ + q0 + l15) * D_ + quad * 8;
    const bf16x8 a_qh = *(const bf16x8*)(qh + qbase);
    const long kv_bh = (long)bh * S_ * D_;
    const u64* mrow = mbits + ((long)b * S_ + q0 + quad * 4) * 16;

    // ---- inline QR (2 MFMAs + LDS transpose) ----
    bf16x8 a_qr;
    {
        #pragma unroll
        for (int nt = 0; nt < 2; ++nt) {
            const float* wp = wrel + (long)(nt * 16 + l15) * 32 + quad * 8;
            float4 w0 = *(const float4*)(wp);
            float4 w1 = *(const float4*)(wp + 4);
            bf16x8 bw;
            *(uint4*)&bw = (uint4){ pk_rne(w0.x, w0.y), pk_rne(w0.z, w0.w),
                                    pk_rne(w1.x, w1.y), pk_rne(w1.z, w1.w) };
            f32x4 z = {0.f, 0.f, 0.f, 0.f};
            f32x4 cq = __builtin_amdgcn_mfma_f32_16x16x32_bf16(a_qh, bw, z, 0, 0, 0);
            #pragma unroll
            for (int r = 0; r < 4; ++r)
                pw0[(quad * 4 + r) * 36 + nt * 16 + l15] = f2b(cq[r]);
        }
        asm volatile("" ::: "memory");
        a_qr = *(const bf16x8*)(pw0 + l15 * 36 + quad * 8);
        asm volatile("" ::: "memory");
    }

    int bidx[4]; int cnd[4];
    #pragma unroll
    for (int r = 0; r < 4; ++r) {
        int qq = quad * 4 + r;
        bidx[r] = (quad * 16 + ((l15 + 15 - qq) & 15)) * 4;
        cnd[r] = (l15 > qq);
    }

    f32x4 oacc[2] = {};
    float l4[4] = {0.f, 0.f, 0.f, 0.f};

    bf16x8 preg0 = {}, preg1 = {};
    bf16x8 bv00 = {}, bv01 = {}, bv10 = {}, bv11 = {};

    // prologue: rel/K fragments for chunk c0
    bf16x8 kf[4], rf[5];
    {
        const int ub0 = c0 * 64 - q0 + (S_ - 15);
        #pragma unroll
        for (int ut = 0; ut < 5; ++ut)
            rf[ut] = *(const bf16x8*)(relb + (long)(ub0 + ut * 16 + l15) * D_ + quad * 8);
        #pragma unroll
        for (int kt = 0; kt < 4; ++kt)
            kf[kt] = *(const bf16x8*)(kh + kv_bh + (long)(c0 * 64 + kt * 16 + l15) * D_ + quad * 8);
    }

    for (int i = 0; i < 8; ++i) {                      // dynamic loop — do not unroll
        const int c = c0 + i;
        const int kbase = c * 64;
        short* pwbuf = (i & 1) ? pw1 : pw0;

        // consume prefetched rel/K fragments (9 independent MFMAs)
        f32x4 ctf[5], sc[4];
        #pragma unroll
        for (int ut = 0; ut < 5; ++ut) {
            f32x4 z = {0.f, 0.f, 0.f, 0.f};
            ctf[ut] = __builtin_amdgcn_mfma_f32_16x16x32_bf16(a_qr, rf[ut], z, 0, 0, 0);
        }
        #pragma unroll
        for (int kt = 0; kt < 4; ++kt) {
            f32x4 z = {0.f, 0.f, 0.f, 0.f};
            sc[kt] = __builtin_amdgcn_mfma_f32_16x16x32_bf16(a_qh, kf[kt], z, 0, 0, 0);
        }
        // PV for previous chunk
        if (i) {
            oacc[0] = __builtin_amdgcn_mfma_f32_16x16x32_bf16(preg0, bv00, oacc[0], 0, 0, 0);
            oacc[1] = __builtin_amdgcn_mfma_f32_16x16x32_bf16(preg0, bv01, oacc[1], 0, 0, 0);
            oacc[0] = __builtin_amdgcn_mfma_f32_16x16x32_bf16(preg1, bv10, oacc[0], 0, 0, 0);
            oacc[1] = __builtin_amdgcn_mfma_f32_16x16x32_bf16(preg1, bv11, oacc[1], 0, 0, 0);
        }
        // prefetch rel/K for next chunk (clamped, reuses same regs) + V for this chunk
        {
            const int cn = c + ((i < 7) ? 1 : 0);
            const int kbn = cn * 64, ubn = kbn - q0 + (S_ - 15);
            #pragma unroll
            for (int ut = 0; ut < 5; ++ut)
                rf[ut] = *(const bf16x8*)(relb + (long)(ubn + ut * 16 + l15) * D_ + quad * 8);
            #pragma unroll
            for (int kt = 0; kt < 4; ++kt)
                kf[kt] = *(const bf16x8*)(kh + kv_bh + (long)(kbn + kt * 16 + l15) * D_ + quad * 8);
        }
        bv00 = *(const bf16x8*)(vt + kv_bh + (long)(l15) * S_ + kbase + quad * 8);
        bv01 = *(const bf16x8*)(vt + kv_bh + (long)(16 + l15) * S_ + kbase + quad * 8);
        bv10 = *(const bf16x8*)(vt + kv_bh + (long)(l15) * S_ + kbase + 32 + quad * 8);
        bv11 = *(const bf16x8*)(vt + kv_bh + (long)(16 + l15) * S_ + kbase + 32 + quad * 8);

        // bias shear (bpermute) + straight-sum exp + inline mask
        #pragma unroll
        for (int r = 0; r < 4; ++r) {
            float tt[5];
            #pragma unroll
            for (int ut = 0; ut < 5; ++ut) tt[ut] = bperm(bidx[r], ctf[ut][r]);
            float s0 = sc[0][r] + (cnd[r] ? tt[1] : tt[0]);
            float s1 = sc[1][r] + (cnd[r] ? tt[2] : tt[1]);
            float s2 = sc[2][r] + (cnd[r] ? tt[3] : tt[2]);
            float s3 = sc[3][r] + (cnd[r] ? tt[4] : tt[3]);
            u64 mw = mrow[r * 16 + c] >> l15;
            unsigned lo = (unsigned)mw, hi = (unsigned)(mw >> 32);
            float p0 = __expf(s0); p0 = (lo & 1u)         ? p0 : 0.f;
            float p1 = __expf(s1); p1 = ((lo >> 16) & 1u) ? p1 : 0.f;
            float p2 = __expf(s2); p2 = (hi & 1u)         ? p2 : 0.f;
            float p3 = __expf(s3); p3 = ((hi >> 16) & 1u) ? p3 : 0.f;
            l4[r] += (p0 + p1) + (p2 + p3);
            u64 pv = ((u64)pk_trunc(p2, p3) << 32) | (u64)pk_trunc(p0, p1);
            *(u64*)(pwbuf + (quad * 4 + r) * 72 + l15 * 4) = pv;
        }
        asm volatile("" ::: "memory");
        preg0 = *(const bf16x8*)(pwbuf + l15 * 72 + quad * 8);
        preg1 = *(const bf16x8*)(pwbuf + l15 * 72 + 32 + quad * 8);
    }
    // final PV
    oacc[0] = __builtin_amdgcn_mfma_f32_16x16x32_bf16(preg0, bv00, oacc[0], 0, 0, 0);
    oacc[1] = __builtin_amdgcn_mfma_f32_16x16x32_bf16(preg0, bv01, oacc[1], 0, 0, 0);
    oacc[0] = __builtin_amdgcn_mfma_f32_16x16x32_bf16(preg1, bv10, oacc[0], 0, 0, 0);
    oacc[1] = __builtin_amdgcn_mfma_f32_16x16x32_bf16(preg1, bv11, oacc[1], 0, 0, 0);

    // per-wave row sums
    #pragma unroll
    for (int r = 0; r < 4; ++r) {
        float l = l4[r];
        l += __shfl_xor(l, 1, 64);
        l += __shfl_xor(l, 2, 64);
        l += __shfl_xor(l, 4, 64);
        l += __shfl_xor(l, 8, 64);
        l4[r] = l;
    }

    // cross-half combine: write partials into own (now dead) P area, sync, half 0 adds
    asm volatile("" ::: "memory");
    float* fo = (float*)pw0;                           // [16 rows][32 d] f32 (2048B < 2304B)
    float* fl = (float*)pw1;                           // [16 rows] f32
    #pragma unroll
    for (int r = 0; r < 4; ++r) {
        #pragma unroll
        for (int dt = 0; dt < 2; ++dt)
            fo[(quad * 4 + r) * 32 + dt * 16 + l15] = oacc[dt][r];
        if (l15 == 0) fl[quad * 4 + r] = l4[r];
    }
    __syncthreads();
    if (half == 0) {
        const float* po = (const float*)(smem + (w ^ 1) * (2 * 16 * 72));
        const float* pl = po + 576;                    // partner pw1 as float*
        #pragma unroll
        for (int r = 0; r < 4; ++r) {
            int row = quad * 4 + r;
            float inv = 1.0f / (l4[r] + pl[row]);
            #pragma unroll
            for (int dt = 0; dt < 2; ++dt) {
                float o = oacc[dt][r] + po[row * 32 + dt * 16 + l15];
                ao[((long)(b * S_ + q0 + row) * H_ + h) * D_ + dt * 16 + l15] = f2b(o * inv);
            }
        }
    }
}

extern "C" void kernel_launch(void* const* d_in, const int* in_sizes, int n_in,
                              void* d_out, int out_size, void* d_ws, size_t ws_size,
                              hipStream_t stream) {
    (void)in_sizes; (void)n_in; (void)out_size; (void)ws_size;
    const float* kv   = (const float*)d_in[0];
    const float* q    = (const float*)d_in[1];
    const int*   mask = (const int*)d_in[2];
    const float* Wq   = (const float*)d_in[3];
    const float* Wk   = (const float*)d_in[4];
    const float* Wv   = (const float*)d_in[5];
    const float* Wo   = (const float*)d_in[6];
    const float* rt   = (const float*)d_in[7];
    const float* Wrel = (const float*)d_in[8];

    // workspace map — 18.75 MB total (proven safe)
    char* ws = (char*)d_ws;
    short* qh   = (short*)(ws);                      // [B,H,S,D] bf16, 4MB
    short* kh   = (short*)(ws + (4u  << 20));        // [B,H,S,D] 4MB
    short* vt   = (short*)(ws + (8u  << 20));        // [B,H,D,S'] k-permuted, 4MB
    short* ao   = (short*)(ws + (12u << 20));        // [B,S,H,D] 4MB
    short* Wt   = (short*)(ws + (16u << 20));        // 4x[512n][512k] bf16, 2MB
    short* relb = (short*)(ws + (18u << 20));        // [2049,32] bf16, 128KB
    u64*  mbits = (u64*) (ws + (18u << 20) + (256u << 10));  // 512KB

    const float scale = 0.17677669529663687f;        // 1/sqrt(32) folded into QH (and thus QR)

    prep_kernel<<<257 + 4096 + 1024, 256, 0, stream>>>(
        rt, relb, mask, mbits, Wq, Wk, Wv, Wo, Wt);

    gemm3_kernel<<<1536, 256, 0, stream>>>(q, kv, Wt, qh, kh, vt, scale);

    attn_kernel<<<2048, 256, 0, stream>>>(qh, Wrel, kh, vt, relb, mbits, ao);

    gemm_out_kernel<<<512, 256, 0, stream>>>(ao, Wt, (float*)d_out);
}

// Round 9
// 191.947 us; speedup vs baseline: 1.4718x; 1.1863x over previous
//
#include <hip/hip_runtime.h>

#define S_ 1024
#define H_ 16
#define D_ 32

typedef float f32x4 __attribute__((ext_vector_type(4)));
typedef short bf16x8 __attribute__((ext_vector_type(8)));
typedef unsigned long long u64;

static __device__ __forceinline__ short f2b(float f) {
    union { float f; unsigned u; } x; x.f = f;
    unsigned u = x.u;
    unsigned r = u + 0x7fffu + ((u >> 16) & 1u);
    return (short)(r >> 16);
}
static __device__ __forceinline__ unsigned pk_rne(float lo, float hi) {
    union { float f; unsigned u; } a, b; a.f = lo; b.f = hi;
    unsigned ul = a.u + 0x7fffu + ((a.u >> 16) & 1u);
    unsigned uh = b.u + 0x7fffu + ((b.u >> 16) & 1u);
    return __builtin_amdgcn_perm(uh, ul, 0x07060302u);
}
static __device__ __forceinline__ unsigned pk_trunc(float lo, float hi) {
    union { float f; unsigned u; } a, b; a.f = lo; b.f = hi;
    return __builtin_amdgcn_perm(b.u, a.u, 0x07060302u);
}
static __device__ __forceinline__ float bperm(int bidx, float v) {
    union { float f; int i; } x; x.f = v;
    x.i = __builtin_amdgcn_ds_bpermute(bidx, x.i);
    return x.f;
}
// LDS staging offset, 64-col tiles (pitch 72), XOR swizzle
static __device__ __forceinline__ int stg64(int row, int c8) {
    return row * 72 + (c8 ^ ((row & 3) << 3));
}

// ---------------- prep: relb cvt + mask pack + W transpose ----------------
__global__ __launch_bounds__(256)
void prep_kernel(const float* __restrict__ rt, short* __restrict__ relb,
                 const int* __restrict__ mask, u64* __restrict__ mbits,
                 const float* __restrict__ Wq, const float* __restrict__ Wk,
                 const float* __restrict__ Wv, const float* __restrict__ Wo,
                 short* __restrict__ Wt)
{
    __shared__ float ls[32][33];
    int bid = blockIdx.x, t = threadIdx.x;
    if (bid < 257) {                                   // rel_table -> bf16 (65568 elems)
        int i = bid * 256 + t;
        if (i < 2049 * 32) relb[i] = f2b(rt[i]);
        return;
    }
    bid -= 257;
    if (bid < 4096) {                                  // mask bit-pack (4M ints -> 64K u64)
        #pragma unroll
        for (int j = 0; j < 4; ++j) {
            int i = bid * 1024 + j * 256 + t;
            u64 bal = __ballot(mask[i] > 0);
            if ((t & 63) == 0) mbits[i >> 6] = bal;
        }
        return;
    }
    bid -= 4096;                                       // W transpose -> bf16 [mat][n][k], 1024 blocks
    int mat = bid >> 8, tl = bid & 255, ti = tl >> 4, tj = tl & 15;
    const float* W = (mat == 0) ? Wq : (mat == 1) ? Wk : (mat == 2) ? Wv : Wo;
    int r = t >> 3, c = (t & 7) * 4;
    float4 v = *(const float4*)(W + (long)(ti * 32 + r) * 512 + tj * 32 + c);
    ls[r][c] = v.x; ls[r][c + 1] = v.y; ls[r][c + 2] = v.z; ls[r][c + 3] = v.w;
    __syncthreads();
    int nl = t >> 3, kk = (t & 7) * 4;
    uint2 o = { pk_rne(ls[kk][nl], ls[kk + 1][nl]),
                pk_rne(ls[kk + 2][nl], ls[kk + 3][nl]) };
    *(uint2*)(Wt + ((long)mat * 512 + tj * 32 + nl) * 512 + ti * 32 + kk) = o;
}

// ---------------- fused projection GEMMs: qh, kh, vt (64x64 tiles, BK=64) ----------------
// Block mapping: bm = bid&63 so the 8 blocks sharing an A-tile are spaced 64 apart
// (== same XCD under round-robin dispatch) -> A-tile L2 reuse instead of 8x HBM fetch.
__global__ __launch_bounds__(256)
void gemm3_kernel(const float* __restrict__ q, const float* __restrict__ kv,
                  const short* __restrict__ Wt,
                  short* __restrict__ qh, short* __restrict__ kh, short* __restrict__ vt,
                  float scale)
{
    __shared__ __align__(16) short a_s[64 * 72];
    __shared__ __align__(16) short b_s[64 * 72];
    const int t = threadIdx.x;
    const int w = t >> 6, lane = t & 63, l15 = lane & 15, quad = lane >> 4;
    const int wm = w & 1, wn = w >> 1;

    int bid = blockIdx.x;
    const int mat = bid >> 9;                  // 0:q@Wq 1:kv@Wk 2:kv@Wv
    const int rr_ = bid & 511;
    const int bm = (rr_ & 63) * 64, bn = (rr_ >> 6) * 64;   // XCD-grouped
    const float* A = (mat == 0) ? q : kv;
    const short* Wm = Wt + (long)mat * 262144;

    const int srow = t >> 2, scg = (t & 3) << 4;       // row 0..63, col group 0/16/32/48
    f32x4 acc[2][2] = {};

    for (int k0 = 0; k0 < 512; k0 += 64) {
        {
            const float* ap = A + (long)(bm + srow) * 512 + k0 + scg;
            float4 v0 = *(const float4*)(ap);
            float4 v1 = *(const float4*)(ap + 4);
            float4 v2 = *(const float4*)(ap + 8);
            float4 v3 = *(const float4*)(ap + 12);
            uint4 o0 = { pk_rne(v0.x, v0.y), pk_rne(v0.z, v0.w),
                         pk_rne(v1.x, v1.y), pk_rne(v1.z, v1.w) };
            uint4 o1 = { pk_rne(v2.x, v2.y), pk_rne(v2.z, v2.w),
                         pk_rne(v3.x, v3.y), pk_rne(v3.z, v3.w) };
            *(uint4*)(a_s + stg64(srow, scg)) = o0;
            *(uint4*)(a_s + stg64(srow, scg + 8)) = o1;
        }
        {
            const short* bp = Wm + (long)(bn + srow) * 512 + k0 + scg;
            *(bf16x8*)(b_s + stg64(srow, scg))     = *(const bf16x8*)(bp);
            *(bf16x8*)(b_s + stg64(srow, scg + 8)) = *(const bf16x8*)(bp + 8);
        }
        __syncthreads();
        bf16x8 af[2][2], bfr[2][2];
        #pragma unroll
        for (int i = 0; i < 2; ++i)
            #pragma unroll
            for (int ks = 0; ks < 2; ++ks) {
                af[i][ks]  = *(const bf16x8*)(a_s + stg64(wm * 32 + i * 16 + l15, ks * 32 + quad * 8));
                bfr[i][ks] = *(const bf16x8*)(b_s + stg64(wn * 32 + i * 16 + l15, ks * 32 + quad * 8));
            }
        if (mat == 2) {
            #pragma unroll
            for (int i = 0; i < 2; ++i)
                #pragma unroll
                for (int j = 0; j < 2; ++j)
                    #pragma unroll
                    for (int ks = 0; ks < 2; ++ks)
                        acc[i][j] = __builtin_amdgcn_mfma_f32_16x16x32_bf16(bfr[i][ks], af[j][ks], acc[i][j], 0, 0, 0);
        } else {
            #pragma unroll
            for (int i = 0; i < 2; ++i)
                #pragma unroll
                for (int j = 0; j < 2; ++j)
                    #pragma unroll
                    for (int ks = 0; ks < 2; ++ks)
                        acc[i][j] = __builtin_amdgcn_mfma_f32_16x16x32_bf16(af[i][ks], bfr[j][ks], acc[i][j], 0, 0, 0);
        }
        __syncthreads();
    }

    if (mat < 2) {
        short* out = (mat == 0) ? qh : kh;
        float alpha = (mat == 0) ? scale : 1.0f;
        #pragma unroll
        for (int i = 0; i < 2; ++i)
            #pragma unroll
            for (int j = 0; j < 2; ++j)
                #pragma unroll
                for (int r = 0; r < 4; ++r) {
                    int m = bm + wm * 32 + i * 16 + quad * 4 + r;
                    int n = bn + wn * 32 + j * 16 + l15;
                    int bb = m >> 10, s = m & 1023, hh = n >> 5, dd = n & 31;
                    out[((long)((bb * 16 + hh) * 1024 + s)) * 32 + dd] = f2b(acc[i][j][r] * alpha);
                }
    } else {
        #pragma unroll
        for (int i = 0; i < 2; ++i)
            #pragma unroll
            for (int j = 0; j < 2; ++j)
                #pragma unroll
                for (int r = 0; r < 4; ++r) {
                    int n = bn + wn * 32 + i * 16 + quad * 4 + r;   // feature (h,d)
                    int m = bm + wm * 32 + j * 16 + l15;            // token
                    int bb = m >> 10, s = m & 1023, hh = n >> 5, dd = n & 31;
                    int sp = (s & ~63) | ((s & 15) << 2) | ((s >> 4) & 3); // k-permute
                    vt[((long)((bb * 16 + hh) * 32 + dd)) * 1024 + sp] = f2b(acc[i][j][r]);
                }
    }
}

// ---------------- output GEMM: d_out = ao @ Wo (BK=64) ----------------
__global__ __launch_bounds__(256)
void gemm_out_kernel(const short* __restrict__ ao, const short* __restrict__ Wt,
                     float* __restrict__ out)
{
    __shared__ __align__(16) short a_s[64 * 72];
    __shared__ __align__(16) short b_s[64 * 72];
    const int t = threadIdx.x;
    const int w = t >> 6, lane = t & 63, l15 = lane & 15, quad = lane >> 4;
    const int wm = w & 1, wn = w >> 1;
    const int bm = (blockIdx.x & 63) * 64, bn = (blockIdx.x >> 6) * 64;  // XCD-grouped
    const short* Wm = Wt + (long)3 * 262144;
    const int srow = t >> 2, scg = (t & 3) << 4;
    f32x4 acc[2][2] = {};

    for (int k0 = 0; k0 < 512; k0 += 64) {
        {
            const short* apb = ao + (long)(bm + srow) * 512 + k0 + scg;
            *(bf16x8*)(a_s + stg64(srow, scg))     = *(const bf16x8*)(apb);
            *(bf16x8*)(a_s + stg64(srow, scg + 8)) = *(const bf16x8*)(apb + 8);
            const short* bpb = Wm + (long)(bn + srow) * 512 + k0 + scg;
            *(bf16x8*)(b_s + stg64(srow, scg))     = *(const bf16x8*)(bpb);
            *(bf16x8*)(b_s + stg64(srow, scg + 8)) = *(const bf16x8*)(bpb + 8);
        }
        __syncthreads();
        bf16x8 af[2][2], bfr[2][2];
        #pragma unroll
        for (int i = 0; i < 2; ++i)
            #pragma unroll
            for (int ks = 0; ks < 2; ++ks) {
                af[i][ks]  = *(const bf16x8*)(a_s + stg64(wm * 32 + i * 16 + l15, ks * 32 + quad * 8));
                bfr[i][ks] = *(const bf16x8*)(b_s + stg64(wn * 32 + i * 16 + l15, ks * 32 + quad * 8));
            }
        #pragma unroll
        for (int i = 0; i < 2; ++i)
            #pragma unroll
            for (int j = 0; j < 2; ++j)
                #pragma unroll
                for (int ks = 0; ks < 2; ++ks)
                    acc[i][j] = __builtin_amdgcn_mfma_f32_16x16x32_bf16(af[i][ks], bfr[j][ks], acc[i][j], 0, 0, 0);
        __syncthreads();
    }
    #pragma unroll
    for (int i = 0; i < 2; ++i)
        #pragma unroll
        for (int j = 0; j < 2; ++j)
            #pragma unroll
            for (int r = 0; r < 4; ++r) {
                int m = bm + wm * 32 + i * 16 + quad * 4 + r;
                int n = bn + wn * 32 + j * 16 + l15;
                out[(long)m * 512 + n] = acc[i][j][r];
            }
}

// ---------------- fused attention v7: 2-way split-K, no-spill register budget ----------------
// NO __launch_bounds__ min-wave arg: r5-r8 showed (256,4) makes the allocator pin 64 arch
// VGPRs and spill to scratch (r8: 35MB of WRITE_SIZE). Shear is done immediately after the
// rel MFMAs (frees ctf's 20 regs before sc's 16 exist); rel/K loads are inline (L2-resident).
__global__ __launch_bounds__(256)
void attn_kernel(const short* __restrict__ qh, const float* __restrict__ wrel,
                 const short* __restrict__ kh, const short* __restrict__ vt,
                 const short* __restrict__ relb, const u64* __restrict__ mbits,
                 short* __restrict__ ao)
{
    __shared__ __align__(16) short smem[4 * 2 * 16 * 72];
    const int t = threadIdx.x;
    const int w = t >> 6, lane = t & 63, l15 = lane & 15, quad = lane >> 4;
    short* pw0 = smem + w * (2 * 16 * 72);
    short* pw1 = pw0 + 16 * 72;

    const int half = w & 1, qsel = w >> 1;
    const int gw = blockIdx.x * 2 + qsel;              // q-tile id, 0..4095
    const int qt = gw & 63, h = (gw >> 6) & 15, b = gw >> 10;
    const int q0 = qt * 16, bh = b * H_ + h;
    const int c0 = half * 8;

    const long qbase = ((long)bh * S_ + q0 + l15) * D_ + quad * 8;
    const bf16x8 a_qh = *(const bf16x8*)(qh + qbase);
    const long kv_bh = (long)bh * S_ * D_;
    const u64* mrow = mbits + ((long)b * S_ + q0 + quad * 4) * 16;

    // ---- inline QR (2 MFMAs + LDS transpose) ----
    bf16x8 a_qr;
    {
        #pragma unroll
        for (int nt = 0; nt < 2; ++nt) {
            const float* wp = wrel + (long)(nt * 16 + l15) * 32 + quad * 8;
            float4 w0 = *(const float4*)(wp);
            float4 w1 = *(const float4*)(wp + 4);
            bf16x8 bw;
            *(uint4*)&bw = (uint4){ pk_rne(w0.x, w0.y), pk_rne(w0.z, w0.w),
                                    pk_rne(w1.x, w1.y), pk_rne(w1.z, w1.w) };
            f32x4 z = {0.f, 0.f, 0.f, 0.f};
            f32x4 cq = __builtin_amdgcn_mfma_f32_16x16x32_bf16(a_qh, bw, z, 0, 0, 0);
            #pragma unroll
            for (int r = 0; r < 4; ++r)
                pw0[(quad * 4 + r) * 36 + nt * 16 + l15] = f2b(cq[r]);
        }
        asm volatile("" ::: "memory");
        a_qr = *(const bf16x8*)(pw0 + l15 * 36 + quad * 8);
        asm volatile("" ::: "memory");
    }

    int bidx[4];
    #pragma unroll
    for (int r = 0; r < 4; ++r)
        bidx[r] = (quad * 16 + ((l15 + 15 - (quad * 4 + r)) & 15)) * 4;

    f32x4 oacc[2] = {};
    float l4[4] = {0.f, 0.f, 0.f, 0.f};

    bf16x8 preg0 = {}, preg1 = {};
    bf16x8 bv00 = {}, bv01 = {}, bv10 = {}, bv11 = {};

    for (int i = 0; i < 8; ++i) {                      // dynamic loop — do not unroll
        const int c = c0 + i;
        const int kbase = c * 64;
        const int ub = kbase - q0 + (S_ - 15);
        short* pwbuf = (i & 1) ? pw1 : pw0;

        // rel MFMAs (inline loads), then shear IMMEDIATELY -> bb (frees ctf)
        float bb[4][4];
        {
            f32x4 ctf[5];
            #pragma unroll
            for (int ut = 0; ut < 5; ++ut) {
                bf16x8 bre = *(const bf16x8*)(relb + (long)(ub + ut * 16 + l15) * D_ + quad * 8);
                f32x4 z = {0.f, 0.f, 0.f, 0.f};
                ctf[ut] = __builtin_amdgcn_mfma_f32_16x16x32_bf16(a_qr, bre, z, 0, 0, 0);
            }
            #pragma unroll
            for (int r = 0; r < 4; ++r) {
                int cnd = l15 > quad * 4 + r;
                float tt[5];
                #pragma unroll
                for (int ut = 0; ut < 5; ++ut) tt[ut] = bperm(bidx[r], ctf[ut][r]);
                bb[r][0] = cnd ? tt[1] : tt[0];
                bb[r][1] = cnd ? tt[2] : tt[1];
                bb[r][2] = cnd ? tt[3] : tt[2];
                bb[r][3] = cnd ? tt[4] : tt[3];
            }
        }
        // QK MFMAs (inline loads)
        f32x4 sc[4];
        #pragma unroll
        for (int kt = 0; kt < 4; ++kt) {
            bf16x8 bk = *(const bf16x8*)(kh + kv_bh + (long)(kbase + kt * 16 + l15) * D_ + quad * 8);
            f32x4 z = {0.f, 0.f, 0.f, 0.f};
            sc[kt] = __builtin_amdgcn_mfma_f32_16x16x32_bf16(a_qh, bk, z, 0, 0, 0);
        }
        // PV for previous chunk
        if (i) {
            oacc[0] = __builtin_amdgcn_mfma_f32_16x16x32_bf16(preg0, bv00, oacc[0], 0, 0, 0);
            oacc[1] = __builtin_amdgcn_mfma_f32_16x16x32_bf16(preg0, bv01, oacc[1], 0, 0, 0);
            oacc[0] = __builtin_amdgcn_mfma_f32_16x16x32_bf16(preg1, bv10, oacc[0], 0, 0, 0);
            oacc[1] = __builtin_amdgcn_mfma_f32_16x16x32_bf16(preg1, bv11, oacc[1], 0, 0, 0);
        }
        // V prefetch for this chunk (consumed next iter / epilogue)
        bv00 = *(const bf16x8*)(vt + kv_bh + (long)(l15) * S_ + kbase + quad * 8);
        bv01 = *(const bf16x8*)(vt + kv_bh + (long)(16 + l15) * S_ + kbase + quad * 8);
        bv10 = *(const bf16x8*)(vt + kv_bh + (long)(l15) * S_ + kbase + 32 + quad * 8);
        bv11 = *(const bf16x8*)(vt + kv_bh + (long)(16 + l15) * S_ + kbase + 32 + quad * 8);

        // straight-sum exp + inline mask + P pack/store
        #pragma unroll
        for (int r = 0; r < 4; ++r) {
            float s0 = sc[0][r] + bb[r][0];
            float s1 = sc[1][r] + bb[r][1];
            float s2 = sc[2][r] + bb[r][2];
            float s3 = sc[3][r] + bb[r][3];
            u64 mw = mrow[r * 16 + c] >> l15;
            unsigned lo = (unsigned)mw, hi = (unsigned)(mw >> 32);
            float p0 = __expf(s0); p0 = (lo & 1u)         ? p0 : 0.f;
            float p1 = __expf(s1); p1 = ((lo >> 16) & 1u) ? p1 : 0.f;
            float p2 = __expf(s2); p2 = (hi & 1u)         ? p2 : 0.f;
            float p3 = __expf(s3); p3 = ((hi >> 16) & 1u) ? p3 : 0.f;
            l4[r] += (p0 + p1) + (p2 + p3);
            u64 pv = ((u64)pk_trunc(p2, p3) << 32) | (u64)pk_trunc(p0, p1);
            *(u64*)(pwbuf + (quad * 4 + r) * 72 + l15 * 4) = pv;
        }
        asm volatile("" ::: "memory");
        preg0 = *(const bf16x8*)(pwbuf + l15 * 72 + quad * 8);
        preg1 = *(const bf16x8*)(pwbuf + l15 * 72 + 32 + quad * 8);
    }
    // final PV
    oacc[0] = __builtin_amdgcn_mfma_f32_16x16x32_bf16(preg0, bv00, oacc[0], 0, 0, 0);
    oacc[1] = __builtin_amdgcn_mfma_f32_16x16x32_bf16(preg0, bv01, oacc[1], 0, 0, 0);
    oacc[0] = __builtin_amdgcn_mfma_f32_16x16x32_bf16(preg1, bv10, oacc[0], 0, 0, 0);
    oacc[1] = __builtin_amdgcn_mfma_f32_16x16x32_bf16(preg1, bv11, oacc[1], 0, 0, 0);

    // per-wave row sums
    #pragma unroll
    for (int r = 0; r < 4; ++r) {
        float l = l4[r];
        l += __shfl_xor(l, 1, 64);
        l += __shfl_xor(l, 2, 64);
        l += __shfl_xor(l, 4, 64);
        l += __shfl_xor(l, 8, 64);
        l4[r] = l;
    }

    // cross-half combine: write partials into own (now dead) P area, sync, half 0 adds
    asm volatile("" ::: "memory");
    float* fo = (float*)pw0;                           // [16 rows][32 d] f32 (2048B < 2304B)
    float* fl = (float*)pw1;                           // [16 rows] f32
    #pragma unroll
    for (int r = 0; r < 4; ++r) {
        #pragma unroll
        for (int dt = 0; dt < 2; ++dt)
            fo[(quad * 4 + r) * 32 + dt * 16 + l15] = oacc[dt][r];
        if (l15 == 0) fl[quad * 4 + r] = l4[r];
    }
    __syncthreads();
    if (half == 0) {
        const float* po = (const float*)(smem + (w ^ 1) * (2 * 16 * 72));
        const float* pl = po + 576;                    // partner pw1 as float*
        #pragma unroll
        for (int r = 0; r < 4; ++r) {
            int row = quad * 4 + r;
            float inv = 1.0f / (l4[r] + pl[row]);
            #pragma unroll
            for (int dt = 0; dt < 2; ++dt) {
                float o = oacc[dt][r] + po[row * 32 + dt * 16 + l15];
                ao[((long)(b * S_ + q0 + row) * H_ + h) * D_ + dt * 16 + l15] = f2b(o * inv);
            }
        }
    }
}

extern "C" void kernel_launch(void* const* d_in, const int* in_sizes, int n_in,
                              void* d_out, int out_size, void* d_ws, size_t ws_size,
                              hipStream_t stream) {
    (void)in_sizes; (void)n_in; (void)out_size; (void)ws_size;
    const float* kv   = (const float*)d_in[0];
    const float* q    = (const float*)d_in[1];
    const int*   mask = (const int*)d_in[2];
    const float* Wq   = (const float*)d_in[3];
    const float* Wk   = (const float*)d_in[4];
    const float* Wv   = (const float*)d_in[5];
    const float* Wo   = (const float*)d_in[6];
    const float* rt   = (const float*)d_in[7];
    const float* Wrel = (const float*)d_in[8];

    // workspace map — 18.75 MB total (proven safe)
    char* ws = (char*)d_ws;
    short* qh   = (short*)(ws);                      // [B,H,S,D] bf16, 4MB
    short* kh   = (short*)(ws + (4u  << 20));        // [B,H,S,D] 4MB
    short* vt   = (short*)(ws + (8u  << 20));        // [B,H,D,S'] k-permuted, 4MB
    short* ao   = (short*)(ws + (12u << 20));        // [B,S,H,D] 4MB
    short* Wt   = (short*)(ws + (16u << 20));        // 4x[512n][512k] bf16, 2MB
    short* relb = (short*)(ws + (18u << 20));        // [2049,32] bf16, 128KB
    u64*  mbits = (u64*) (ws + (18u << 20) + (256u << 10));  // 512KB

    const float scale = 0.17677669529663687f;        // 1/sqrt(32) folded into QH (and thus QR)

    prep_kernel<<<257 + 4096 + 1024, 256, 0, stream>>>(
        rt, relb, mask, mbits, Wq, Wk, Wv, Wo, Wt);

    gemm3_kernel<<<1536, 256, 0, stream>>>(q, kv, Wt, qh, kh, vt, scale);

    attn_kernel<<<2048, 256, 0, stream>>>(qh, Wrel, kh, vt, relb, mbits, ao);

    gemm_out_kernel<<<512, 256, 0, stream>>>(ao, Wt, (float*)d_out);
}